// Round 12
// baseline (87180.365 us; speedup 1.0000x reference)
//
#include <hip/hip_runtime.h>

// Problem constants (V,E,H,T,L) = (32000,1024,1024,512,4096), E==H==1024.
#define L_SEQ   4096
#define HDIM    1024
#define THREE_H 3072
#define TDIM    512
#define PUBW    2048   // words per pub buffer: 4 domains * 512 packed words

typedef __attribute__((ext_vector_type(8))) short bf16x8;   // 8 bf16 = 4 VGPRs
typedef __attribute__((ext_vector_type(4))) float f32x4;
typedef __attribute__((ext_vector_type(2))) unsigned u32x2;

__device__ __forceinline__ unsigned short f2bf(float f) {
  unsigned u = __float_as_uint(f);
  unsigned r = (u + 0x7FFFu + ((u >> 16) & 1u)) >> 16;  // RTN-even
  return (unsigned short)r;
}
__device__ __forceinline__ float bf2f(unsigned short u) {
  return __uint_as_float(((unsigned)u) << 16);
}
__device__ __forceinline__ float sigm(float x) { return 1.f / (1.f + __expf(-x)); }
__device__ __forceinline__ float tanh_f(float x) {
  float e = __expf(2.f * x);
  return 1.f - 2.f / (e + 1.f);   // correct limits at +-inf
}

// XCD-local poll: atomic-OR-0 with sc0 (= return-old, L2 execution point).
// Atomics NEVER execute in vL1 -> immune to R7's stale-L1 tag alias. No sc1
// -> the RMW is served by THIS XCD's L2 (~0.1-0.2us), not Infinity Cache.
__device__ __forceinline__ unsigned atomic_poll(const unsigned* p) {
  unsigned r;
  asm volatile("global_atomic_or %0, %1, %2, off sc0\n\ts_waitcnt vmcnt(0)"
               : "=v"(r) : "v"(p), "v"(0u) : "memory");
  return r;
}
// Publish: plain store — CDNA vL1 is write-through, so it lands in the local
// XCD L2 where the domain's atomics observe it.
__device__ __forceinline__ void st8_plain(unsigned* p, unsigned lo, unsigned hi) {
  u32x2 v; v[0] = lo; v[1] = hi;
  asm volatile("global_store_dwordx2 %0, %1, off" :: "v"(p), "v"(v) : "memory");
}

// ---------------------------------------------------------------------------
// k_init: BOTH pub buffers <- packed {bf16(h[2w]), bf16(h[2w+1])}, word-LSB
// tag = 1 (R11 layout: pub[buf][dom][w], flat = buf*2048 + dom*512 + w).
// Zero the per-XCD rank counters. Cross-XCD visibility of these plain stores
// to the scan is guaranteed by kernel-boundary L2 writeback (evidenced
// R3-R6: init stores were always correctly observed by sc1 IC reads).
// ---------------------------------------------------------------------------
__global__ void k_init(const float* __restrict__ hidden, unsigned* __restrict__ pub,
                       int* __restrict__ cnt) {
  int idx = blockIdx.x * 256 + threadIdx.x;   // 0..4095
  if (idx < 2 * PUBW) {
    int rem = idx & (PUBW - 1);
    int dom = rem >> 9, w = rem & 511;
    int dir = dom >> 1;
    unsigned b0 = f2bf(hidden[dir * HDIM + 2 * w]);
    unsigned b1 = f2bf(hidden[dir * HDIM + 2 * w + 1]);
    pub[idx] = (b0 | (b1 << 16)) | 1u;
  }
  if (idx < 8) cnt[idx] = 0;
}

// ---------------------------------------------------------------------------
// k_embed: x_bf16[s][t][e] = bf16(emb[sent_s[t]][e])
// ---------------------------------------------------------------------------
__global__ void k_embed(const int* __restrict__ sA, const int* __restrict__ sB,
                        const float* __restrict__ emb, unsigned short* __restrict__ xbf) {
  int r = blockIdx.x;        // token position
  int s = blockIdx.y;        // sentence
  int tok = (s ? sB : sA)[r];
  const float* src = emb + (size_t)tok * HDIM;
  float4 v = *(const float4*)(src + threadIdx.x * 4);
  ushort4 o;
  o.x = f2bf(v.x); o.y = f2bf(v.y); o.z = f2bf(v.z); o.w = f2bf(v.w);
  *(ushort4*)(xbf + ((size_t)s * L_SEQ + r) * HDIM + threadIdx.x * 4) = o;
}

// ---------------------------------------------------------------------------
// k_castw: w_ih_{f,r} (3072x1024 f32) -> bf16, concatenated [2][3072][1024]
// ---------------------------------------------------------------------------
__global__ void k_castw(const float* __restrict__ wf, const float* __restrict__ wr,
                        unsigned short* __restrict__ wbf) {
  size_t flat = ((size_t)blockIdx.x * 256 + threadIdx.x) * 8;
  const size_t half = (size_t)THREE_H * HDIM;
  int m = flat >= half;
  const float* src = (m ? wr : wf) + (flat - (m ? half : 0));
  float4 a = *(const float4*)src;
  float4 b = *(const float4*)(src + 4);
  ushort4 o1, o2;
  o1.x = f2bf(a.x); o1.y = f2bf(a.y); o1.z = f2bf(a.z); o1.w = f2bf(a.w);
  o2.x = f2bf(b.x); o2.y = f2bf(b.y); o2.z = f2bf(b.z); o2.w = f2bf(b.w);
  *(ushort4*)(wbf + flat) = o1;
  *(ushort4*)(wbf + flat + 4) = o2;
}

// ---------------------------------------------------------------------------
// k_gemm: gxT[z][j][t] = sum_k w_ih[d][j][k] * x[s][t][k]   (z = d*2+s)
// M=3072 (j), N=4096 (t), K=1024. 128x128 tile, 4 waves, 16x16x32 bf16 MFMA.
// Output stored TRANSPOSED (row=j, col=t) so the scan streams along t.
// ---------------------------------------------------------------------------
__global__ void __launch_bounds__(256)
k_gemm(const unsigned short* __restrict__ wbf,
       const unsigned short* __restrict__ xbf,
       unsigned short* __restrict__ gxT) {
  __shared__ short As[128 * 32];
  __shared__ short Bs[128 * 32];
  const int mb = blockIdx.x, nb = blockIdx.y, z = blockIdx.z;
  const int d = z >> 1, s = z & 1;
  const unsigned short* A = wbf + (size_t)d * THREE_H * HDIM;
  const unsigned short* B = xbf + (size_t)s * L_SEQ * HDIM;
  unsigned short* C = gxT + (size_t)z * THREE_H * L_SEQ;
  const int m0 = mb * 128, n0 = nb * 128;
  const int tid = threadIdx.x;
  const int lane = tid & 63, wid = tid >> 6;
  const int wr = wid >> 1, wc = wid & 1;
  f32x4 acc[4][4] = {};

  for (int kt = 0; kt < 32; ++kt) {
    const int k0 = kt * 32;
#pragma unroll
    for (int j = 0; j < 2; ++j) {
      int c = tid + j * 256;
      int row = c >> 2, sl = c & 3;
      int sl2 = sl ^ ((row >> 1) & 3);
      int4 va = *(const int4*)(A + (size_t)(m0 + row) * HDIM + k0 + sl * 8);
      int4 vb = *(const int4*)(B + (size_t)(n0 + row) * HDIM + k0 + sl * 8);
      *(int4*)&As[row * 32 + sl2 * 8] = va;
      *(int4*)&Bs[row * 32 + sl2 * 8] = vb;
    }
    __syncthreads();
    const int q = lane >> 4, rl = lane & 15;
    bf16x8 af[4], bfr[4];
#pragma unroll
    for (int fm = 0; fm < 4; ++fm) {
      int row = wr * 64 + fm * 16 + rl;
      int q2 = q ^ ((row >> 1) & 3);
      af[fm] = *(const bf16x8*)&As[row * 32 + q2 * 8];
    }
#pragma unroll
    for (int fn = 0; fn < 4; ++fn) {
      int row = wc * 64 + fn * 16 + rl;
      int q2 = q ^ ((row >> 1) & 3);
      bfr[fn] = *(const bf16x8*)&Bs[row * 32 + q2 * 8];
    }
#pragma unroll
    for (int fm = 0; fm < 4; ++fm)
#pragma unroll
      for (int fn = 0; fn < 4; ++fn)
        acc[fm][fn] = __builtin_amdgcn_mfma_f32_16x16x32_bf16(af[fm], bfr[fn], acc[fm][fn], 0, 0, 0);
    __syncthreads();
  }
  const int q = lane >> 4, rl = lane & 15;
#pragma unroll
  for (int fm = 0; fm < 4; ++fm)
#pragma unroll
    for (int fn = 0; fn < 4; ++fn)
#pragma unroll
      for (int j = 0; j < 4; ++j) {
        int row = m0 + wr * 64 + fm * 16 + q * 4 + j;
        int col = n0 + wc * 64 + fn * 16 + rl;
        C[(size_t)row * L_SEQ + col] = f2bf(acc[fm][fn][j]);
      }
}

// ---------------------------------------------------------------------------
// k_scan: XCD-LOCAL domains. 512 blocks x 512 thr = exactly 2 blocks/CU
// capacity (launch_bounds (512,4) caps VGPR at 128 >= the ~120 needed), so
// every XCD hosts exactly 64 blocks. Each block reads its physical XCD
// (s_getreg XCC_ID) and claims rank via device-scope atomicAdd; workers are
// rank<32 on XCDs 0-3, dom = xcd -> all 32 blocks of a domain ARE on one
// XCD. Sync ops hit that XCD's L2 (~0.1-0.2us) instead of IC (~1us):
//   poll    = global_atomic_or(p,0) sc0  (L2-point RMW, L1-immune)
//   publish = plain store              (vL1 write-through -> local L2)
// R7's failure (sc0 LOADS served stale from vL1, period-4 tag alias) is
// structurally impossible here. Budget bail -> loud fast failure if any
// semantic assumption is wrong.
//
// Work layout + protocol VERBATIM R11 (passed, absmax 0.0): sub=rank owns
// 32 i; wave wid owns i4=sub*32+wid*4; 16-lane group owns i4+grp, 64-elem
// k-slice/lane; packed pub word w={bf16(h[2w]),bf16(h[2w+1])}, word-LSB tag;
// step t publishes into pub[t&1] tag (t>>1)&1, gather reads pub[(t+1)&1]
// expecting tag ((t+3)>>1)&1; own-state hp stays exact f32. Earliest
// overwrite of step-t data is t+2 which requires all domain blocks past
// barrier(t+1) >= all gather(t+1) >= gather(t).
// ---------------------------------------------------------------------------
__global__ void __launch_bounds__(512, 4)
k_scan(const float* __restrict__ whf, const float* __restrict__ whr,
       const float* __restrict__ bihf, const float* __restrict__ bhhf,
       const float* __restrict__ bihr, const float* __restrict__ bhhr,
       const float* __restrict__ hidden,
       const unsigned short* __restrict__ gxT,
       float* __restrict__ hout, unsigned* pub, int* cnt) {
  __shared__ float Hs[2][HDIM];   // double-buffered gathered h (f32, unpacked)
  __shared__ int bc;
  const int tid = threadIdx.x;

  int xcd;
  asm("s_getreg_b32 %0, hwreg(HW_REG_XCC_ID)" : "=s"(xcd));
  if (tid == 0) bc = atomicAdd(&cnt[xcd], 1);   // device-scope rank claim
  __syncthreads();
  const int rank = bc;
  if (xcd >= 4 || rank >= 32) return;           // uniform per block

  const int dom = xcd;            // domain = this XCD; dir = dom>>1
  const int sub = rank;           // 0..31
  const int lane = tid & 63, wid = tid >> 6;
  const int i4 = sub * 32 + wid * 4;   // wave's 4 hidden indices
  const int grp = lane >> 4;           // 16-lane group -> owns i4+grp
  const int gl  = lane & 15;           // lane within group (k dimension)

  const int dir = dom >> 1;
  const float* W   = dir ? whr : whf;
  const float* bih = dir ? bihr : bihf;
  const float* bhh = dir ? bhhr : bhhf;

  // ---- load + pack weights: wv[gate][m][pair], k = m*64 + gl*4 + {0..3}
  unsigned wv[3][16][2];
#pragma unroll
  for (int g = 0; g < 3; ++g) {
    const float* wrow = &W[(size_t)(g * HDIM + i4 + grp) * HDIM];
#pragma unroll
    for (int m = 0; m < 16; ++m) {
      float4 w4 = *(const float4*)&wrow[m * 64 + gl * 4];
      wv[g][m][0] = ((unsigned)f2bf(w4.x)) | (((unsigned)f2bf(w4.y)) << 16);
      wv[g][m][1] = ((unsigned)f2bf(w4.z)) | (((unsigned)f2bf(w4.w)) << 16);
    }
  }

  // ---- per-group gate constants + gx stream pointers + OWN h register
  float biR = 0, biZ = 0, biN = 0, bhR = 0, bhZ = 0, bhN = 0, hp = 0;
  const unsigned short *gR = gxT, *gZ = gxT, *gN = gxT;
  {
    int i = i4 + grp;
    biR = bih[i]; biZ = bih[HDIM + i]; biN = bih[2 * HDIM + i];
    bhR = bhh[i]; bhZ = bhh[HDIM + i]; bhN = bhh[2 * HDIM + i];
    hp  = hidden[dir * HDIM + i];   // exact f32 own-state (recurrent term)
    gR = gxT + ((size_t)dom * THREE_H + 0 * HDIM + i) * L_SEQ;
    gZ = gxT + ((size_t)dom * THREE_H + 1 * HDIM + i) * L_SEQ;
    gN = gxT + ((size_t)dom * THREE_H + 2 * HDIM + i) * L_SEQ;
  }

  const int gword = dom * 512 + tid;   // this thread's single packed word
  long budget = 1000000;

  for (int t = 0; t < L_SEQ; ++t) {
    const int col = dir ? (L_SEQ - 1 - t) : t;
    const unsigned expect = (unsigned)(((t + 3) >> 1) & 1);
    const int b = t & 1;

    // gx prefetch (group-lead lanes; drained by the poll's vmcnt alongside
    // the previous publish store — combined, not serial)
    float gaR = 0, gaZ = 0, gaN = 0;
    if (gl == 0) { gaR = bf2f(gR[col]); gaZ = bf2f(gZ[col]); gaN = bf2f(gN[col]); }

    // ---- all-gather: ONE L2-point atomic per round per thread
    const unsigned* src = pub + ((t + 1) & 1) * PUBW + gword;
    unsigned w0;
    int spin = 0;
    for (;;) {
      w0 = atomic_poll(src);
      if ((w0 & 1u) == expect) break;
      if (++spin > 8) __builtin_amdgcn_s_sleep(1);
      if (--budget < 0) break;
    }
    // unpack (tag stripped) to f32 LDS: i=2*tid (lo half), i=2*tid+1 (hi half)
    *(float2*)&Hs[b][tid * 2] =
        make_float2(__uint_as_float((w0 & 0xFFFEu) << 16),
                    __uint_as_float(w0 & 0xFFFF0000u));
    __syncthreads();   // hardware barrier (R10: LDS-counter splits are 2x worse)

    // ---- 3 dots (gates r,z,n) for this group's i over its 64-elem k-slices
    float aR = 0.f, aZ = 0.f, aN = 0.f;
#pragma unroll
    for (int m = 0; m < 16; ++m) {
      float4 h4 = *(const float4*)&Hs[b][m * 64 + gl * 4];
      unsigned u0, u1;
      u0 = wv[0][m][0]; u1 = wv[0][m][1];
      aR += __uint_as_float(u0 << 16) * h4.x + __uint_as_float(u0 & 0xFFFF0000u) * h4.y +
            __uint_as_float(u1 << 16) * h4.z + __uint_as_float(u1 & 0xFFFF0000u) * h4.w;
      u0 = wv[1][m][0]; u1 = wv[1][m][1];
      aZ += __uint_as_float(u0 << 16) * h4.x + __uint_as_float(u0 & 0xFFFF0000u) * h4.y +
            __uint_as_float(u1 << 16) * h4.z + __uint_as_float(u1 & 0xFFFF0000u) * h4.w;
      u0 = wv[2][m][0]; u1 = wv[2][m][1];
      aN += __uint_as_float(u0 << 16) * h4.x + __uint_as_float(u0 & 0xFFFF0000u) * h4.y +
            __uint_as_float(u1 << 16) * h4.z + __uint_as_float(u1 & 0xFFFF0000u) * h4.w;
    }
    // reduce within the 16-lane group (4 levels)
#pragma unroll
    for (int off = 8; off >= 1; off >>= 1) {
      aR += __shfl_xor(aR, off); aZ += __shfl_xor(aZ, off); aN += __shfl_xor(aN, off);
    }

    // ---- gates on group-lead lanes (PyTorch order r,z,n); exact own-state hp
    float hv = 0.f;
    if (gl == 0) {
      float r = sigm(gaR + biR + aR + bhR);
      float z = sigm(gaZ + biZ + aZ + bhZ);
      float n = tanh_f(gaN + biN + r * (aN + bhN));
      hv = (1.f - z) * n + z * hp;
      hp = hv;
      if (t == L_SEQ - 1) hout[dom * HDIM + i4 + grp] = hv;
    }
    // collect the wave's 4 h_new values onto lane 0, publish as ONE 8B store
    float h0 = __shfl(hv, 0), h1 = __shfl(hv, 16), h2 = __shfl(hv, 32), h3 = __shfl(hv, 48);
    const unsigned tag = (unsigned)((t >> 1) & 1);
    if (lane == 0) {
      unsigned w01 = ((unsigned)f2bf(h0) | ((unsigned)f2bf(h1) << 16));
      unsigned w23 = ((unsigned)f2bf(h2) | ((unsigned)f2bf(h3) << 16));
      w01 = (w01 & ~1u) | tag;
      w23 = (w23 & ~1u) | tag;
      st8_plain(pub + b * PUBW + dom * 512 + (i4 >> 1), w01, w23);
    }
    // no trailing barrier: Hs double-buffered; causality proof in header
  }
}

// ---------------------------------------------------------------------------
// k_head1: per output unit r of W2: hq4[r][c] = relu(Ht[c] . W2[r] + b2[r])
// Ht[0]=|hAf-hBf| Ht[1]=hAf*hBf Ht[2]=|hAb-hBb| Ht[3]=hAb*hBb
// hout layout: [dom][i], dom=(dir<<1)|sent -> hAf=+0, hBf=+H, hAb=+2H, hBb=+3H
// ---------------------------------------------------------------------------
__global__ void k_head1(const float* __restrict__ h, const float* __restrict__ W2,
                        const float* __restrict__ b2, float* __restrict__ hq4) {
  __shared__ float red[4][4];
  const int r = blockIdx.x, tid = threadIdx.x;
  const int lane = tid & 63, wid = tid >> 6;
  const float* hAf = h;
  const float* hBf = h + HDIM;
  const float* hAb = h + 2 * HDIM;
  const float* hBb = h + 3 * HDIM;
  float4 w  = *(const float4*)&W2[(size_t)r * HDIM + tid * 4];
  float4 af = *(const float4*)&hAf[tid * 4];
  float4 bf = *(const float4*)&hBf[tid * 4];
  float4 ab = *(const float4*)&hAb[tid * 4];
  float4 bb = *(const float4*)&hBb[tid * 4];
  float p0 = fabsf(af.x - bf.x) * w.x + fabsf(af.y - bf.y) * w.y +
             fabsf(af.z - bf.z) * w.z + fabsf(af.w - bf.w) * w.w;
  float p1 = (af.x * bf.x) * w.x + (af.y * bf.y) * w.y +
             (af.z * bf.z) * w.z + (af.w * bf.w) * w.w;
  float p2 = fabsf(ab.x - bb.x) * w.x + fabsf(ab.y - bb.y) * w.y +
             fabsf(ab.z - bb.z) * w.z + fabsf(ab.w - bb.w) * w.w;
  float p3 = (ab.x * bb.x) * w.x + (ab.y * bb.y) * w.y +
             (ab.z * bb.z) * w.z + (ab.w * bb.w) * w.w;
#pragma unroll
  for (int off = 32; off >= 1; off >>= 1) {
    p0 += __shfl_xor(p0, off); p1 += __shfl_xor(p1, off);
    p2 += __shfl_xor(p2, off); p3 += __shfl_xor(p3, off);
  }
  if (lane == 0) { red[wid][0] = p0; red[wid][1] = p1; red[wid][2] = p2; red[wid][3] = p3; }
  __syncthreads();
  if (tid == 0) {
    float v0 = 0, v1 = 0, v2 = 0, v3 = 0;
    for (int wv = 0; wv < 4; ++wv) { v0 += red[wv][0]; v1 += red[wv][1]; v2 += red[wv][2]; v3 += red[wv][3]; }
    float b = b2[r];
    hq4[r * 4 + 0] = fmaxf(v0 + b, 0.f);
    hq4[r * 4 + 1] = fmaxf(v1 + b, 0.f);
    hq4[r * 4 + 2] = fmaxf(v2 + b, 0.f);
    hq4[r * 4 + 3] = fmaxf(v3 + b, 0.f);
  }
}

__global__ void k_head2(const float* __restrict__ hq4, const float* __restrict__ Wl,
                        const float* __restrict__ bl, float* __restrict__ out) {
  __shared__ float red[4][4];
  const int tid = threadIdx.x, lane = tid & 63, wid = tid >> 6;
  float p0 = 0, p1 = 0, p2 = 0, p3 = 0;
  for (int r = tid; r < TDIM; r += 256) {
    p0 += hq4[r * 4 + 0]; p1 += hq4[r * 4 + 1];
    p2 += hq4[r * 4 + 2]; p3 += hq4[r * 4 + 3];
  }
#pragma unroll
  for (int off = 32; off >= 1; off >>= 1) {
    p0 += __shfl_xor(p0, off); p1 += __shfl_xor(p1, off);
    p2 += __shfl_xor(p2, off); p3 += __shfl_xor(p3, off);
  }
  if (lane == 0) { red[wid][0] = p0; red[wid][1] = p1; red[wid][2] = p2; red[wid][3] = p3; }
  __syncthreads();
  if (tid == 0) {
    float v0 = 0, v1 = 0, v2 = 0, v3 = 0;
    for (int wv = 0; wv < 4; ++wv) { v0 += red[wv][0]; v1 += red[wv][1]; v2 += red[wv][2]; v3 += red[wv][3]; }
    float logit = v0 * Wl[0] + v1 * Wl[1] + v2 * Wl[2] + v3 * Wl[3] + bl[0];
    out[0] = 1.f / (1.f + __expf(-logit));
  }
}

// ---------------------------------------------------------------------------
extern "C" void kernel_launch(void* const* d_in, const int* in_sizes, int n_in,
                              void* d_out, int out_size, void* d_ws, size_t ws_size,
                              hipStream_t stream) {
  const int*   sentA  = (const int*)d_in[0];
  const int*   sentB  = (const int*)d_in[1];
  const float* hidden = (const float*)d_in[2];
  const float* emb    = (const float*)d_in[3];
  const float* w_ih_f = (const float*)d_in[4];
  const float* w_hh_f = (const float*)d_in[5];
  const float* b_ih_f = (const float*)d_in[6];
  const float* b_hh_f = (const float*)d_in[7];
  const float* w_ih_r = (const float*)d_in[8];
  const float* w_hh_r = (const float*)d_in[9];
  const float* b_ih_r = (const float*)d_in[10];
  const float* b_hh_r = (const float*)d_in[11];
  const float* W2     = (const float*)d_in[12];
  const float* b2     = (const float*)d_in[13];
  const float* Wl     = (const float*)d_in[14];
  const float* bl     = (const float*)d_in[15];
  float* out = (float*)d_out;

  // workspace layout (16B-aligned)
  char* ws = (char*)d_ws;
  unsigned short* xbf = (unsigned short*)(ws);              // 2*4096*1024*2  = 16,777,216
  unsigned short* wbf = (unsigned short*)(ws + 16777216);   // 2*3072*1024*2  = 12,582,912
  unsigned short* gxT = (unsigned short*)(ws + 29360128);   // 4*3072*4096*2  = 100,663,296
  float*    hout = (float*)(ws + 130023424);                // 4*1024*4       = 16,384
  unsigned* pub  = (unsigned*)(ws + 130039808);             // 2*2048*4       = 16,384
  int*      cnt  = (int*)(ws + 130056192);                  // 8*4 (pad 1KiB)
  float*    hq4  = (float*)(ws + 130057216);                // 512*4*4        = 8,192

  k_init <<<dim3(16),        256, 0, stream>>>(hidden, pub, cnt);
  k_embed<<<dim3(4096, 2),   256, 0, stream>>>(sentA, sentB, emb, xbf);
  k_castw<<<dim3(3072),      256, 0, stream>>>(w_ih_f, w_ih_r, wbf);
  k_gemm <<<dim3(24, 32, 4), 256, 0, stream>>>(wbf, xbf, gxT);
  k_scan <<<dim3(512),       512, 0, stream>>>(w_hh_f, w_hh_r, b_ih_f, b_hh_f,
                                               b_ih_r, b_hh_r, hidden, gxT, hout, pub, cnt);
  k_head1<<<dim3(512),       256, 0, stream>>>(hout, W2, b2, hq4);
  k_head2<<<dim3(1),         256, 0, stream>>>(hq4, Wl, bl, out);
}

// Round 13
// 12734.326 us; speedup vs baseline: 6.8461x; 6.8461x over previous
//
#include <hip/hip_runtime.h>

// Problem constants (V,E,H,T,L) = (32000,1024,1024,512,4096), E==H==1024.
#define L_SEQ   4096
#define HDIM    1024
#define THREE_H 3072
#define TDIM    512
#define PUBW    2048   // words per pub buffer: 4 domains * 512 packed words

typedef __attribute__((ext_vector_type(8))) short bf16x8;   // 8 bf16 = 4 VGPRs
typedef __attribute__((ext_vector_type(4))) float f32x4;
typedef __attribute__((ext_vector_type(2))) unsigned u32x2;

__device__ __forceinline__ unsigned short f2bf(float f) {
  unsigned u = __float_as_uint(f);
  unsigned r = (u + 0x7FFFu + ((u >> 16) & 1u)) >> 16;  // RTN-even
  return (unsigned short)r;
}
__device__ __forceinline__ float bf2f(unsigned short u) {
  return __uint_as_float(((unsigned)u) << 16);
}
__device__ __forceinline__ float sigm(float x) { return 1.f / (1.f + __expf(-x)); }
__device__ __forceinline__ float tanh_f(float x) {
  float e = __expf(2.f * x);
  return 1.f - 2.f / (e + 1.f);   // correct limits at +-inf
}

// XCD-local poll: atomic-OR-0 with sc0 (= return-old, L2 execution point).
// Atomics NEVER execute in vL1 -> immune to R7's stale-L1 tag alias (PROVEN
// by R12: absmax 0.0 across 4096 steps). No sc1 -> the RMW is served by THIS
// XCD's L2, not Infinity Cache.
__device__ __forceinline__ unsigned atomic_poll(const unsigned* p) {
  unsigned r;
  asm volatile("global_atomic_or %0, %1, %2, off sc0\n\ts_waitcnt vmcnt(0)"
               : "=v"(r) : "v"(p), "v"(0u) : "memory");
  return r;
}
// Publish: plain store — CDNA vL1 is write-through, so it lands in the local
// XCD L2 where the domain's atomics observe it (R12-proven).
__device__ __forceinline__ void st8_plain(unsigned* p, unsigned lo, unsigned hi) {
  u32x2 v; v[0] = lo; v[1] = hi;
  asm volatile("global_store_dwordx2 %0, %1, off" :: "v"(p), "v"(v) : "memory");
}

// ---------------------------------------------------------------------------
// k_init: BOTH pub buffers <- packed {bf16(h[2w]), bf16(h[2w+1])}, word-LSB
// tag = 1 (layout: pub[buf][dom][w], flat = buf*2048 + dom*512 + w).
// Zero the per-XCD rank counters. Cross-XCD visibility of these plain stores
// to the scan is via kernel-boundary L2 writeback (evidenced R3-R6, R12).
// ---------------------------------------------------------------------------
__global__ void k_init(const float* __restrict__ hidden, unsigned* __restrict__ pub,
                       int* __restrict__ cnt) {
  int idx = blockIdx.x * 256 + threadIdx.x;   // 0..4095
  if (idx < 2 * PUBW) {
    int rem = idx & (PUBW - 1);
    int dom = rem >> 9, w = rem & 511;
    int dir = dom >> 1;
    unsigned b0 = f2bf(hidden[dir * HDIM + 2 * w]);
    unsigned b1 = f2bf(hidden[dir * HDIM + 2 * w + 1]);
    pub[idx] = (b0 | (b1 << 16)) | 1u;
  }
  if (idx < 8) cnt[idx] = 0;
}

// ---------------------------------------------------------------------------
// k_embed: x_bf16[s][t][e] = bf16(emb[sent_s[t]][e])
// ---------------------------------------------------------------------------
__global__ void k_embed(const int* __restrict__ sA, const int* __restrict__ sB,
                        const float* __restrict__ emb, unsigned short* __restrict__ xbf) {
  int r = blockIdx.x;        // token position
  int s = blockIdx.y;        // sentence
  int tok = (s ? sB : sA)[r];
  const float* src = emb + (size_t)tok * HDIM;
  float4 v = *(const float4*)(src + threadIdx.x * 4);
  ushort4 o;
  o.x = f2bf(v.x); o.y = f2bf(v.y); o.z = f2bf(v.z); o.w = f2bf(v.w);
  *(ushort4*)(xbf + ((size_t)s * L_SEQ + r) * HDIM + threadIdx.x * 4) = o;
}

// ---------------------------------------------------------------------------
// k_castw: w_ih_{f,r} (3072x1024 f32) -> bf16, concatenated [2][3072][1024]
// ---------------------------------------------------------------------------
__global__ void k_castw(const float* __restrict__ wf, const float* __restrict__ wr,
                        unsigned short* __restrict__ wbf) {
  size_t flat = ((size_t)blockIdx.x * 256 + threadIdx.x) * 8;
  const size_t half = (size_t)THREE_H * HDIM;
  int m = flat >= half;
  const float* src = (m ? wr : wf) + (flat - (m ? half : 0));
  float4 a = *(const float4*)src;
  float4 b = *(const float4*)(src + 4);
  ushort4 o1, o2;
  o1.x = f2bf(a.x); o1.y = f2bf(a.y); o1.z = f2bf(a.z); o1.w = f2bf(a.w);
  o2.x = f2bf(b.x); o2.y = f2bf(b.y); o2.z = f2bf(b.z); o2.w = f2bf(b.w);
  *(ushort4*)(wbf + flat) = o1;
  *(ushort4*)(wbf + flat + 4) = o2;
}

// ---------------------------------------------------------------------------
// k_gemm: gxT[z][j][t] = sum_k w_ih[d][j][k] * x[s][t][k]   (z = d*2+s)
// M=3072 (j), N=4096 (t), K=1024. 128x128 tile, 4 waves, 16x16x32 bf16 MFMA.
// Output stored TRANSPOSED (row=j, col=t) so the scan streams along t.
// ---------------------------------------------------------------------------
__global__ void __launch_bounds__(256)
k_gemm(const unsigned short* __restrict__ wbf,
       const unsigned short* __restrict__ xbf,
       unsigned short* __restrict__ gxT) {
  __shared__ short As[128 * 32];
  __shared__ short Bs[128 * 32];
  const int mb = blockIdx.x, nb = blockIdx.y, z = blockIdx.z;
  const int d = z >> 1, s = z & 1;
  const unsigned short* A = wbf + (size_t)d * THREE_H * HDIM;
  const unsigned short* B = xbf + (size_t)s * L_SEQ * HDIM;
  unsigned short* C = gxT + (size_t)z * THREE_H * L_SEQ;
  const int m0 = mb * 128, n0 = nb * 128;
  const int tid = threadIdx.x;
  const int lane = tid & 63, wid = tid >> 6;
  const int wr = wid >> 1, wc = wid & 1;
  f32x4 acc[4][4] = {};

  for (int kt = 0; kt < 32; ++kt) {
    const int k0 = kt * 32;
#pragma unroll
    for (int j = 0; j < 2; ++j) {
      int c = tid + j * 256;
      int row = c >> 2, sl = c & 3;
      int sl2 = sl ^ ((row >> 1) & 3);
      int4 va = *(const int4*)(A + (size_t)(m0 + row) * HDIM + k0 + sl * 8);
      int4 vb = *(const int4*)(B + (size_t)(n0 + row) * HDIM + k0 + sl * 8);
      *(int4*)&As[row * 32 + sl2 * 8] = va;
      *(int4*)&Bs[row * 32 + sl2 * 8] = vb;
    }
    __syncthreads();
    const int q = lane >> 4, rl = lane & 15;
    bf16x8 af[4], bfr[4];
#pragma unroll
    for (int fm = 0; fm < 4; ++fm) {
      int row = wr * 64 + fm * 16 + rl;
      int q2 = q ^ ((row >> 1) & 3);
      af[fm] = *(const bf16x8*)&As[row * 32 + q2 * 8];
    }
#pragma unroll
    for (int fn = 0; fn < 4; ++fn) {
      int row = wc * 64 + fn * 16 + rl;
      int q2 = q ^ ((row >> 1) & 3);
      bfr[fn] = *(const bf16x8*)&Bs[row * 32 + q2 * 8];
    }
#pragma unroll
    for (int fm = 0; fm < 4; ++fm)
#pragma unroll
      for (int fn = 0; fn < 4; ++fn)
        acc[fm][fn] = __builtin_amdgcn_mfma_f32_16x16x32_bf16(af[fm], bfr[fn], acc[fm][fn], 0, 0, 0);
    __syncthreads();
  }
  const int q = lane >> 4, rl = lane & 15;
#pragma unroll
  for (int fm = 0; fm < 4; ++fm)
#pragma unroll
    for (int fn = 0; fn < 4; ++fn)
#pragma unroll
      for (int j = 0; j < 4; ++j) {
        int row = m0 + wr * 64 + fm * 16 + q * 4 + j;
        int col = n0 + wc * 64 + fn * 16 + rl;
        C[(size_t)row * L_SEQ + col] = f2bf(acc[fm][fn][j]);
      }
}

// ---------------------------------------------------------------------------
// k_scan: XCD-LOCAL domains, R12 semantics (absmax 0.0 PROVEN) with the
// R6/R11-proven register budget: __launch_bounds__(512, 1) -> compiler gave
// VGPR=120 twice for this body (R12's (512,4) let the allocator target 8
// waves/EU -> 64 VGPRs -> wv spilled -> 57 GB scratch traffic).
//
// 512 blocks x 512 thr. At VGPR=120 hardware occupancy is 2 blocks/CU
// (waves/CU halves at 128) -> 64 blocks/XCD; even at 1 block/CU the initial
// residency is 32/XCD — either way every XCD 0-3 gets >=32 claimants.
// Each block reads its physical XCD (s_getreg XCC_ID) and claims rank via
// device-scope atomicAdd; workers are rank<32 on XCDs 0-3, dom = xcd.
// Sync ops hit that XCD's L2:
//   poll    = global_atomic_or(p,0) sc0  (L2-point RMW, L1-immune)
//   publish = plain store                (vL1 write-through -> local L2)
// Budget bail -> loud fast failure if any semantic assumption breaks.
//
// Work layout + protocol VERBATIM R11/R12: sub=rank owns 32 i; wave wid owns
// i4=sub*32+wid*4; 16-lane group owns i4+grp, 64-elem k-slice/lane; packed
// pub word w={bf16(h[2w]),bf16(h[2w+1])}, word-LSB tag; step t publishes
// into pub[t&1] tag (t>>1)&1, gather reads pub[(t+1)&1] expecting tag
// ((t+3)>>1)&1; own-state hp stays exact f32. Earliest overwrite of step-t
// data is t+2, requiring all domain blocks past barrier(t+1) >= gather(t).
// ---------------------------------------------------------------------------
__global__ void __launch_bounds__(512, 1)
k_scan(const float* __restrict__ whf, const float* __restrict__ whr,
       const float* __restrict__ bihf, const float* __restrict__ bhhf,
       const float* __restrict__ bihr, const float* __restrict__ bhhr,
       const float* __restrict__ hidden,
       const unsigned short* __restrict__ gxT,
       float* __restrict__ hout, unsigned* pub, int* cnt) {
  __shared__ float Hs[2][HDIM];   // double-buffered gathered h (f32, unpacked)
  __shared__ int bc;
  const int tid = threadIdx.x;

  int xcd;
  asm("s_getreg_b32 %0, hwreg(HW_REG_XCC_ID)" : "=s"(xcd));
  if (tid == 0) bc = atomicAdd(&cnt[xcd], 1);   // device-scope rank claim
  __syncthreads();
  const int rank = bc;
  if (xcd >= 4 || rank >= 32) return;           // uniform per block

  const int dom = xcd;            // domain = this XCD; dir = dom>>1
  const int sub = rank;           // 0..31
  const int lane = tid & 63, wid = tid >> 6;
  const int i4 = sub * 32 + wid * 4;   // wave's 4 hidden indices
  const int grp = lane >> 4;           // 16-lane group -> owns i4+grp
  const int gl  = lane & 15;           // lane within group (k dimension)

  const int dir = dom >> 1;
  const float* W   = dir ? whr : whf;
  const float* bih = dir ? bihr : bihf;
  const float* bhh = dir ? bhhr : bhhf;

  // ---- load + pack weights: wv[gate][m][pair], k = m*64 + gl*4 + {0..3}
  unsigned wv[3][16][2];
#pragma unroll
  for (int g = 0; g < 3; ++g) {
    const float* wrow = &W[(size_t)(g * HDIM + i4 + grp) * HDIM];
#pragma unroll
    for (int m = 0; m < 16; ++m) {
      float4 w4 = *(const float4*)&wrow[m * 64 + gl * 4];
      wv[g][m][0] = ((unsigned)f2bf(w4.x)) | (((unsigned)f2bf(w4.y)) << 16);
      wv[g][m][1] = ((unsigned)f2bf(w4.z)) | (((unsigned)f2bf(w4.w)) << 16);
    }
  }

  // ---- per-group gate constants + gx stream pointers + OWN h register
  float biR = 0, biZ = 0, biN = 0, bhR = 0, bhZ = 0, bhN = 0, hp = 0;
  const unsigned short *gR = gxT, *gZ = gxT, *gN = gxT;
  {
    int i = i4 + grp;
    biR = bih[i]; biZ = bih[HDIM + i]; biN = bih[2 * HDIM + i];
    bhR = bhh[i]; bhZ = bhh[HDIM + i]; bhN = bhh[2 * HDIM + i];
    hp  = hidden[dir * HDIM + i];   // exact f32 own-state (recurrent term)
    gR = gxT + ((size_t)dom * THREE_H + 0 * HDIM + i) * L_SEQ;
    gZ = gxT + ((size_t)dom * THREE_H + 1 * HDIM + i) * L_SEQ;
    gN = gxT + ((size_t)dom * THREE_H + 2 * HDIM + i) * L_SEQ;
  }

  const int gword = dom * 512 + tid;   // this thread's single packed word
  long budget = 1000000;

  for (int t = 0; t < L_SEQ; ++t) {
    const int col = dir ? (L_SEQ - 1 - t) : t;
    const unsigned expect = (unsigned)(((t + 3) >> 1) & 1);
    const int b = t & 1;

    // gx prefetch (group-lead lanes; drained by the poll's vmcnt alongside
    // the previous publish store — combined, not serial)
    float gaR = 0, gaZ = 0, gaN = 0;
    if (gl == 0) { gaR = bf2f(gR[col]); gaZ = bf2f(gZ[col]); gaN = bf2f(gN[col]); }

    // ---- all-gather: ONE L2-point atomic per round per thread
    const unsigned* src = pub + ((t + 1) & 1) * PUBW + gword;
    unsigned w0;
    int spin = 0;
    for (;;) {
      w0 = atomic_poll(src);
      if ((w0 & 1u) == expect) break;
      if (++spin > 8) __builtin_amdgcn_s_sleep(1);
      if (--budget < 0) break;
    }
    // unpack (tag stripped) to f32 LDS: i=2*tid (lo half), i=2*tid+1 (hi half)
    *(float2*)&Hs[b][tid * 2] =
        make_float2(__uint_as_float((w0 & 0xFFFEu) << 16),
                    __uint_as_float(w0 & 0xFFFF0000u));
    __syncthreads();   // hardware barrier (R10: LDS-counter splits are 2x worse)

    // ---- 3 dots (gates r,z,n) for this group's i over its 64-elem k-slices
    float aR = 0.f, aZ = 0.f, aN = 0.f;
#pragma unroll
    for (int m = 0; m < 16; ++m) {
      float4 h4 = *(const float4*)&Hs[b][m * 64 + gl * 4];
      unsigned u0, u1;
      u0 = wv[0][m][0]; u1 = wv[0][m][1];
      aR += __uint_as_float(u0 << 16) * h4.x + __uint_as_float(u0 & 0xFFFF0000u) * h4.y +
            __uint_as_float(u1 << 16) * h4.z + __uint_as_float(u1 & 0xFFFF0000u) * h4.w;
      u0 = wv[1][m][0]; u1 = wv[1][m][1];
      aZ += __uint_as_float(u0 << 16) * h4.x + __uint_as_float(u0 & 0xFFFF0000u) * h4.y +
            __uint_as_float(u1 << 16) * h4.z + __uint_as_float(u1 & 0xFFFF0000u) * h4.w;
      u0 = wv[2][m][0]; u1 = wv[2][m][1];
      aN += __uint_as_float(u0 << 16) * h4.x + __uint_as_float(u0 & 0xFFFF0000u) * h4.y +
            __uint_as_float(u1 << 16) * h4.z + __uint_as_float(u1 & 0xFFFF0000u) * h4.w;
    }
    // reduce within the 16-lane group (4 levels)
#pragma unroll
    for (int off = 8; off >= 1; off >>= 1) {
      aR += __shfl_xor(aR, off); aZ += __shfl_xor(aZ, off); aN += __shfl_xor(aN, off);
    }

    // ---- gates on group-lead lanes (PyTorch order r,z,n); exact own-state hp
    float hv = 0.f;
    if (gl == 0) {
      float r = sigm(gaR + biR + aR + bhR);
      float z = sigm(gaZ + biZ + aZ + bhZ);
      float n = tanh_f(gaN + biN + r * (aN + bhN));
      hv = (1.f - z) * n + z * hp;
      hp = hv;
      if (t == L_SEQ - 1) hout[dom * HDIM + i4 + grp] = hv;
    }
    // collect the wave's 4 h_new values onto lane 0, publish as ONE 8B store
    float h0 = __shfl(hv, 0), h1 = __shfl(hv, 16), h2 = __shfl(hv, 32), h3 = __shfl(hv, 48);
    const unsigned tag = (unsigned)((t >> 1) & 1);
    if (lane == 0) {
      unsigned w01 = ((unsigned)f2bf(h0) | ((unsigned)f2bf(h1) << 16));
      unsigned w23 = ((unsigned)f2bf(h2) | ((unsigned)f2bf(h3) << 16));
      w01 = (w01 & ~1u) | tag;
      w23 = (w23 & ~1u) | tag;
      st8_plain(pub + b * PUBW + dom * 512 + (i4 >> 1), w01, w23);
    }
    // no trailing barrier: Hs double-buffered; causality proof in header
  }
}

// ---------------------------------------------------------------------------
// k_head1: per output unit r of W2: hq4[r][c] = relu(Ht[c] . W2[r] + b2[r])
// Ht[0]=|hAf-hBf| Ht[1]=hAf*hBf Ht[2]=|hAb-hBb| Ht[3]=hAb*hBb
// hout layout: [dom][i], dom=(dir<<1)|sent -> hAf=+0, hBf=+H, hAb=+2H, hBb=+3H
// ---------------------------------------------------------------------------
__global__ void k_head1(const float* __restrict__ h, const float* __restrict__ W2,
                        const float* __restrict__ b2, float* __restrict__ hq4) {
  __shared__ float red[4][4];
  const int r = blockIdx.x, tid = threadIdx.x;
  const int lane = tid & 63, wid = tid >> 6;
  const float* hAf = h;
  const float* hBf = h + HDIM;
  const float* hAb = h + 2 * HDIM;
  const float* hBb = h + 3 * HDIM;
  float4 w  = *(const float4*)&W2[(size_t)r * HDIM + tid * 4];
  float4 af = *(const float4*)&hAf[tid * 4];
  float4 bf = *(const float4*)&hBf[tid * 4];
  float4 ab = *(const float4*)&hAb[tid * 4];
  float4 bb = *(const float4*)&hBb[tid * 4];
  float p0 = fabsf(af.x - bf.x) * w.x + fabsf(af.y - bf.y) * w.y +
             fabsf(af.z - bf.z) * w.z + fabsf(af.w - bf.w) * w.w;
  float p1 = (af.x * bf.x) * w.x + (af.y * bf.y) * w.y +
             (af.z * bf.z) * w.z + (af.w * bf.w) * w.w;
  float p2 = fabsf(ab.x - bb.x) * w.x + fabsf(ab.y - bb.y) * w.y +
             fabsf(ab.z - bb.z) * w.z + fabsf(ab.w - bb.w) * w.w;
  float p3 = (ab.x * bb.x) * w.x + (ab.y * bb.y) * w.y +
             (ab.z * bb.z) * w.z + (ab.w * bb.w) * w.w;
#pragma unroll
  for (int off = 32; off >= 1; off >>= 1) {
    p0 += __shfl_xor(p0, off); p1 += __shfl_xor(p1, off);
    p2 += __shfl_xor(p2, off); p3 += __shfl_xor(p3, off);
  }
  if (lane == 0) { red[wid][0] = p0; red[wid][1] = p1; red[wid][2] = p2; red[wid][3] = p3; }
  __syncthreads();
  if (tid == 0) {
    float v0 = 0, v1 = 0, v2 = 0, v3 = 0;
    for (int wv = 0; wv < 4; ++wv) { v0 += red[wv][0]; v1 += red[wv][1]; v2 += red[wv][2]; v3 += red[wv][3]; }
    float b = b2[r];
    hq4[r * 4 + 0] = fmaxf(v0 + b, 0.f);
    hq4[r * 4 + 1] = fmaxf(v1 + b, 0.f);
    hq4[r * 4 + 2] = fmaxf(v2 + b, 0.f);
    hq4[r * 4 + 3] = fmaxf(v3 + b, 0.f);
  }
}

__global__ void k_head2(const float* __restrict__ hq4, const float* __restrict__ Wl,
                        const float* __restrict__ bl, float* __restrict__ out) {
  __shared__ float red[4][4];
  const int tid = threadIdx.x, lane = tid & 63, wid = tid >> 6;
  float p0 = 0, p1 = 0, p2 = 0, p3 = 0;
  for (int r = tid; r < TDIM; r += 256) {
    p0 += hq4[r * 4 + 0]; p1 += hq4[r * 4 + 1];
    p2 += hq4[r * 4 + 2]; p3 += hq4[r * 4 + 3];
  }
#pragma unroll
  for (int off = 32; off >= 1; off >>= 1) {
    p0 += __shfl_xor(p0, off); p1 += __shfl_xor(p1, off);
    p2 += __shfl_xor(p2, off); p3 += __shfl_xor(p3, off);
  }
  if (lane == 0) { red[wid][0] = p0; red[wid][1] = p1; red[wid][2] = p2; red[wid][3] = p3; }
  __syncthreads();
  if (tid == 0) {
    float v0 = 0, v1 = 0, v2 = 0, v3 = 0;
    for (int wv = 0; wv < 4; ++wv) { v0 += red[wv][0]; v1 += red[wv][1]; v2 += red[wv][2]; v3 += red[wv][3]; }
    float logit = v0 * Wl[0] + v1 * Wl[1] + v2 * Wl[2] + v3 * Wl[3] + bl[0];
    out[0] = 1.f / (1.f + __expf(-logit));
  }
}

// ---------------------------------------------------------------------------
extern "C" void kernel_launch(void* const* d_in, const int* in_sizes, int n_in,
                              void* d_out, int out_size, void* d_ws, size_t ws_size,
                              hipStream_t stream) {
  const int*   sentA  = (const int*)d_in[0];
  const int*   sentB  = (const int*)d_in[1];
  const float* hidden = (const float*)d_in[2];
  const float* emb    = (const float*)d_in[3];
  const float* w_ih_f = (const float*)d_in[4];
  const float* w_hh_f = (const float*)d_in[5];
  const float* b_ih_f = (const float*)d_in[6];
  const float* b_hh_f = (const float*)d_in[7];
  const float* w_ih_r = (const float*)d_in[8];
  const float* w_hh_r = (const float*)d_in[9];
  const float* b_ih_r = (const float*)d_in[10];
  const float* b_hh_r = (const float*)d_in[11];
  const float* W2     = (const float*)d_in[12];
  const float* b2     = (const float*)d_in[13];
  const float* Wl     = (const float*)d_in[14];
  const float* bl     = (const float*)d_in[15];
  float* out = (float*)d_out;

  // workspace layout (16B-aligned)
  char* ws = (char*)d_ws;
  unsigned short* xbf = (unsigned short*)(ws);              // 2*4096*1024*2  = 16,777,216
  unsigned short* wbf = (unsigned short*)(ws + 16777216);   // 2*3072*1024*2  = 12,582,912
  unsigned short* gxT = (unsigned short*)(ws + 29360128);   // 4*3072*4096*2  = 100,663,296
  float*    hout = (float*)(ws + 130023424);                // 4*1024*4       = 16,384
  unsigned* pub  = (unsigned*)(ws + 130039808);             // 2*2048*4       = 16,384
  int*      cnt  = (int*)(ws + 130056192);                  // 8*4 (pad 1KiB)
  float*    hq4  = (float*)(ws + 130057216);                // 512*4*4        = 8,192

  k_init <<<dim3(16),        256, 0, stream>>>(hidden, pub, cnt);
  k_embed<<<dim3(4096, 2),   256, 0, stream>>>(sentA, sentB, emb, xbf);
  k_castw<<<dim3(3072),      256, 0, stream>>>(w_ih_f, w_ih_r, wbf);
  k_gemm <<<dim3(24, 32, 4), 256, 0, stream>>>(wbf, xbf, gxT);
  k_scan <<<dim3(512),       512, 0, stream>>>(w_hh_f, w_hh_r, b_ih_f, b_hh_f,
                                               b_ih_r, b_hh_r, hidden, gxT, hout, pub, cnt);
  k_head1<<<dim3(512),       256, 0, stream>>>(hout, W2, b2, hq4);
  k_head2<<<dim3(1),         256, 0, stream>>>(hq4, Wl, bl, out);
}

// Round 14
// 7923.415 us; speedup vs baseline: 11.0029x; 1.6072x over previous
//
#include <hip/hip_runtime.h>

// Problem constants (V,E,H,T,L) = (32000,1024,1024,512,4096), E==H==1024.
#define L_SEQ   4096
#define HDIM    1024
#define THREE_H 3072
#define TDIM    512
#define PUBW    2048   // words per pub buffer: 4 domains * 512 packed words

typedef __attribute__((ext_vector_type(8))) short bf16x8;   // 8 bf16 = 4 VGPRs
typedef __attribute__((ext_vector_type(4))) float f32x4;
typedef __attribute__((ext_vector_type(2))) unsigned u32x2;

__device__ __forceinline__ unsigned short f2bf(float f) {
  unsigned u = __float_as_uint(f);
  unsigned r = (u + 0x7FFFu + ((u >> 16) & 1u)) >> 16;  // RTN-even
  return (unsigned short)r;
}
__device__ __forceinline__ float bf2f(unsigned short u) {
  return __uint_as_float(((unsigned)u) << 16);
}
__device__ __forceinline__ float sigm(float x) { return 1.f / (1.f + __expf(-x)); }
__device__ __forceinline__ float tanh_f(float x) {
  float e = __expf(2.f * x);
  return 1.f - 2.f / (e + 1.f);   // correct limits at +-inf
}

// Device-coherent (agent-scope sc1 — bypasses L1+L2, served at Infinity Cache;
// PROVEN correct R3-R6/R11; R7 showed sc0 loads are NOT a guaranteed L1
// bypass; R13 showed sc0 L2-atomics serialize + writeback-storm) ops.
__device__ __forceinline__ unsigned ld4_sc1(const unsigned* p) {
  unsigned r;
  asm volatile("global_load_dword %0, %1, off sc1\n\ts_waitcnt vmcnt(0)"
               : "=v"(r) : "v"(p) : "memory");
  return r;
}
__device__ __forceinline__ void st8_sc1(unsigned* p, unsigned lo, unsigned hi) {
  u32x2 v; v[0] = lo; v[1] = hi;
  asm volatile("global_store_dwordx2 %0, %1, off sc1" :: "v"(p), "v"(v) : "memory");
}

// ---------------------------------------------------------------------------
// k_init: BOTH pub buffers <- packed {bf16(h[2w]), bf16(h[2w+1])}, word-LSB
// tag = 1. buf[1] tag 1 = genuine "step -1" publication (t=0 expects tag 1);
// buf[0] tag 1 correctly FAILS t=1's expected tag 0 until step 0 overwrites
// (also neutralizes 0xAA poison whose LSB=0 would alias tag 0).
// Layout: pub[buf][dom][w], flat = buf*2048 + dom*512 + w; w covers i=2w,2w+1.
// dom = dir*2 + sentence; both sentences start from the same hidden[dir].
// ---------------------------------------------------------------------------
__global__ void k_init(const float* __restrict__ hidden, unsigned* __restrict__ pub) {
  int idx = blockIdx.x * 256 + threadIdx.x;   // 0..4095
  if (idx < 2 * PUBW) {
    int rem = idx & (PUBW - 1);
    int dom = rem >> 9, w = rem & 511;
    int dir = dom >> 1;
    unsigned b0 = f2bf(hidden[dir * HDIM + 2 * w]);
    unsigned b1 = f2bf(hidden[dir * HDIM + 2 * w + 1]);
    pub[idx] = (b0 | (b1 << 16)) | 1u;
  }
}

// ---------------------------------------------------------------------------
// k_embed: x_bf16[s][t][e] = bf16(emb[sent_s[t]][e])
// ---------------------------------------------------------------------------
__global__ void k_embed(const int* __restrict__ sA, const int* __restrict__ sB,
                        const float* __restrict__ emb, unsigned short* __restrict__ xbf) {
  int r = blockIdx.x;        // token position
  int s = blockIdx.y;        // sentence
  int tok = (s ? sB : sA)[r];
  const float* src = emb + (size_t)tok * HDIM;
  float4 v = *(const float4*)(src + threadIdx.x * 4);
  ushort4 o;
  o.x = f2bf(v.x); o.y = f2bf(v.y); o.z = f2bf(v.z); o.w = f2bf(v.w);
  *(ushort4*)(xbf + ((size_t)s * L_SEQ + r) * HDIM + threadIdx.x * 4) = o;
}

// ---------------------------------------------------------------------------
// k_castw: w_ih_{f,r} (3072x1024 f32) -> bf16, concatenated [2][3072][1024]
// ---------------------------------------------------------------------------
__global__ void k_castw(const float* __restrict__ wf, const float* __restrict__ wr,
                        unsigned short* __restrict__ wbf) {
  size_t flat = ((size_t)blockIdx.x * 256 + threadIdx.x) * 8;
  const size_t half = (size_t)THREE_H * HDIM;
  int m = flat >= half;
  const float* src = (m ? wr : wf) + (flat - (m ? half : 0));
  float4 a = *(const float4*)src;
  float4 b = *(const float4*)(src + 4);
  ushort4 o1, o2;
  o1.x = f2bf(a.x); o1.y = f2bf(a.y); o1.z = f2bf(a.z); o1.w = f2bf(a.w);
  o2.x = f2bf(b.x); o2.y = f2bf(b.y); o2.z = f2bf(b.z); o2.w = f2bf(b.w);
  *(ushort4*)(wbf + flat) = o1;
  *(ushort4*)(wbf + flat + 4) = o2;
}

// ---------------------------------------------------------------------------
// k_gemm: gxT[z][j][t] = sum_k w_ih[d][j][k] * x[s][t][k]   (z = d*2+s)
// M=3072 (j), N=4096 (t), K=1024. 128x128 tile, 4 waves, 16x16x32 bf16 MFMA.
// Output stored TRANSPOSED (row=j, col=t) so the scan streams along t.
// ---------------------------------------------------------------------------
__global__ void __launch_bounds__(256)
k_gemm(const unsigned short* __restrict__ wbf,
       const unsigned short* __restrict__ xbf,
       unsigned short* __restrict__ gxT) {
  __shared__ short As[128 * 32];
  __shared__ short Bs[128 * 32];
  const int mb = blockIdx.x, nb = blockIdx.y, z = blockIdx.z;
  const int d = z >> 1, s = z & 1;
  const unsigned short* A = wbf + (size_t)d * THREE_H * HDIM;
  const unsigned short* B = xbf + (size_t)s * L_SEQ * HDIM;
  unsigned short* C = gxT + (size_t)z * THREE_H * L_SEQ;
  const int m0 = mb * 128, n0 = nb * 128;
  const int tid = threadIdx.x;
  const int lane = tid & 63, wid = tid >> 6;
  const int wr = wid >> 1, wc = wid & 1;
  f32x4 acc[4][4] = {};

  for (int kt = 0; kt < 32; ++kt) {
    const int k0 = kt * 32;
#pragma unroll
    for (int j = 0; j < 2; ++j) {
      int c = tid + j * 256;
      int row = c >> 2, sl = c & 3;
      int sl2 = sl ^ ((row >> 1) & 3);
      int4 va = *(const int4*)(A + (size_t)(m0 + row) * HDIM + k0 + sl * 8);
      int4 vb = *(const int4*)(B + (size_t)(n0 + row) * HDIM + k0 + sl * 8);
      *(int4*)&As[row * 32 + sl2 * 8] = va;
      *(int4*)&Bs[row * 32 + sl2 * 8] = vb;
    }
    __syncthreads();
    const int q = lane >> 4, rl = lane & 15;
    bf16x8 af[4], bfr[4];
#pragma unroll
    for (int fm = 0; fm < 4; ++fm) {
      int row = wr * 64 + fm * 16 + rl;
      int q2 = q ^ ((row >> 1) & 3);
      af[fm] = *(const bf16x8*)&As[row * 32 + q2 * 8];
    }
#pragma unroll
    for (int fn = 0; fn < 4; ++fn) {
      int row = wc * 64 + fn * 16 + rl;
      int q2 = q ^ ((row >> 1) & 3);
      bfr[fn] = *(const bf16x8*)&Bs[row * 32 + q2 * 8];
    }
#pragma unroll
    for (int fm = 0; fm < 4; ++fm)
#pragma unroll
      for (int fn = 0; fn < 4; ++fn)
        acc[fm][fn] = __builtin_amdgcn_mfma_f32_16x16x32_bf16(af[fm], bfr[fn], acc[fm][fn], 0, 0, 0);
    __syncthreads();
  }
  const int q = lane >> 4, rl = lane & 15;
#pragma unroll
  for (int fm = 0; fm < 4; ++fm)
#pragma unroll
    for (int fn = 0; fn < 4; ++fn)
#pragma unroll
      for (int j = 0; j < 4; ++j) {
        int row = m0 + wr * 64 + fm * 16 + q * 4 + j;
        int col = n0 + wc * 64 + fn * 16 + rl;
        C[(size_t)row * L_SEQ + col] = f2bf(acc[fm][fn][j]);
      }
}

// ---------------------------------------------------------------------------
// k_scan: R11 VERBATIM — the verified optimum (7.96 ms total, absmax 0.0).
// 128 blocks x 512 thr, 4 domains of 32 blocks, dom=bid&3, sub=bid>>2 owns
// 32 i, wave wid owns i4=sub*32+wid*4, 16-lane group owns i4+grp with a
// 64-elem k-slice per lane, w_hh bf16-packed in 96 VGPRs/lane, one
// __syncthreads per step (hardware barrier — R10 proved LDS-counter
// alternatives cost 2.6e8 bank conflicts and 2x time).
//
// PACKED publication (R5-validated numerics class, absmax 0.0): pub word
// w = {bf16(h[2w]) lo, bf16(h[2w+1]) hi}, word-LSB tag. Domain pub surface
// = 512 words (16 IC lines); each thread polls ONE dword; each wave
// publishes 8 B. Consumers strip the tag bit on unpack. Each group-lead
// keeps its OWN h in an f32 register (hp) -> recurrent z*h_old stays exact.
//
// Sync protocol (proven R3-R6): step t publishes into pub[t&1] with tag
// (t>>1)&1; gather at step t reads pub[(t+1)&1] expecting tag ((t+3)>>1)&1.
// Earliest overwrite of step-t data is step t+2, which causally requires
// every domain block past barrier(t+1) ⊇ all gather(t+1) ⊇ gather(t).
//
// Characterized floor: ~1.4us/step = IC publish->observe round trip; all
// alternatives measured and rejected (R7 sc0-loads incorrect; R10 LDS
// split-barriers 2x; R13 L2-atomics 1.6x + writeback storm).
// ---------------------------------------------------------------------------
__global__ void __launch_bounds__(512, 1)
k_scan(const float* __restrict__ whf, const float* __restrict__ whr,
       const float* __restrict__ bihf, const float* __restrict__ bhhf,
       const float* __restrict__ bihr, const float* __restrict__ bhhr,
       const float* __restrict__ hidden,
       const unsigned short* __restrict__ gxT,
       float* __restrict__ hout, unsigned* pub) {
  __shared__ float Hs[2][HDIM];   // double-buffered gathered h (f32, unpacked)
  const int bid = blockIdx.x;
  const int dom = bid & 3;        // dir = dom>>1, sentence = dom&1
  const int sub = bid >> 2;       // 0..31
  const int tid = threadIdx.x;
  const int lane = tid & 63, wid = tid >> 6;
  const int i4 = sub * 32 + wid * 4;   // wave's 4 hidden indices
  const int grp = lane >> 4;           // 16-lane group -> owns i4+grp
  const int gl  = lane & 15;           // lane within group (k dimension)

  const int dir = dom >> 1;
  const float* W   = dir ? whr : whf;
  const float* bih = dir ? bihr : bihf;
  const float* bhh = dir ? bhhr : bhhf;

  // ---- load + pack weights: wv[gate][m][pair], k = m*64 + gl*4 + {0..3}
  unsigned wv[3][16][2];
#pragma unroll
  for (int g = 0; g < 3; ++g) {
    const float* wrow = &W[(size_t)(g * HDIM + i4 + grp) * HDIM];
#pragma unroll
    for (int m = 0; m < 16; ++m) {
      float4 w4 = *(const float4*)&wrow[m * 64 + gl * 4];
      wv[g][m][0] = ((unsigned)f2bf(w4.x)) | (((unsigned)f2bf(w4.y)) << 16);
      wv[g][m][1] = ((unsigned)f2bf(w4.z)) | (((unsigned)f2bf(w4.w)) << 16);
    }
  }

  // ---- per-group gate constants + gx stream pointers + OWN h register
  float biR = 0, biZ = 0, biN = 0, bhR = 0, bhZ = 0, bhN = 0, hp = 0;
  const unsigned short *gR = gxT, *gZ = gxT, *gN = gxT;
  {
    int i = i4 + grp;
    biR = bih[i]; biZ = bih[HDIM + i]; biN = bih[2 * HDIM + i];
    bhR = bhh[i]; bhZ = bhh[HDIM + i]; bhN = bhh[2 * HDIM + i];
    hp  = hidden[dir * HDIM + i];   // exact f32 own-state (recurrent term)
    gR = gxT + ((size_t)dom * THREE_H + 0 * HDIM + i) * L_SEQ;
    gZ = gxT + ((size_t)dom * THREE_H + 1 * HDIM + i) * L_SEQ;
    gN = gxT + ((size_t)dom * THREE_H + 2 * HDIM + i) * L_SEQ;
  }

  const int gword = dom * 512 + tid;   // this thread's single packed word
  long budget = 1000000;

  for (int t = 0; t < L_SEQ; ++t) {
    const int col = dir ? (L_SEQ - 1 - t) : t;
    const unsigned expect = (unsigned)(((t + 3) >> 1) & 1);
    const int b = t & 1;

    // gx prefetch (group-lead lanes; drained by the poll's vmcnt alongside
    // the previous publish store — combined, not serial)
    float gaR = 0, gaZ = 0, gaN = 0;
    if (gl == 0) { gaR = bf2f(gR[col]); gaZ = bf2f(gZ[col]); gaN = bf2f(gN[col]); }

    // ---- all-gather: ONE 4B sc1 load per round (coalesced 256B/wave)
    const unsigned* src = pub + ((t + 1) & 1) * PUBW + gword;
    unsigned w0;
    int spin = 0;
    for (;;) {
      w0 = ld4_sc1(src);
      if ((w0 & 1u) == expect) break;
      if (++spin > 8) __builtin_amdgcn_s_sleep(1);
      if (--budget < 0) break;
    }
    // unpack (tag stripped) to f32 LDS: i=2*tid (lo half), i=2*tid+1 (hi half)
    *(float2*)&Hs[b][tid * 2] =
        make_float2(__uint_as_float((w0 & 0xFFFEu) << 16),
                    __uint_as_float(w0 & 0xFFFF0000u));
    __syncthreads();   // block's gather(t) complete; Hs[b] ready

    // ---- 3 dots (gates r,z,n) for this group's i over its 64-elem k-slices
    float aR = 0.f, aZ = 0.f, aN = 0.f;
#pragma unroll
    for (int m = 0; m < 16; ++m) {
      float4 h4 = *(const float4*)&Hs[b][m * 64 + gl * 4];
      unsigned u0, u1;
      u0 = wv[0][m][0]; u1 = wv[0][m][1];
      aR += __uint_as_float(u0 << 16) * h4.x + __uint_as_float(u0 & 0xFFFF0000u) * h4.y +
            __uint_as_float(u1 << 16) * h4.z + __uint_as_float(u1 & 0xFFFF0000u) * h4.w;
      u0 = wv[1][m][0]; u1 = wv[1][m][1];
      aZ += __uint_as_float(u0 << 16) * h4.x + __uint_as_float(u0 & 0xFFFF0000u) * h4.y +
            __uint_as_float(u1 << 16) * h4.z + __uint_as_float(u1 & 0xFFFF0000u) * h4.w;
      u0 = wv[2][m][0]; u1 = wv[2][m][1];
      aN += __uint_as_float(u0 << 16) * h4.x + __uint_as_float(u0 & 0xFFFF0000u) * h4.y +
            __uint_as_float(u1 << 16) * h4.z + __uint_as_float(u1 & 0xFFFF0000u) * h4.w;
    }
    // reduce within the 16-lane group (4 levels)
#pragma unroll
    for (int off = 8; off >= 1; off >>= 1) {
      aR += __shfl_xor(aR, off); aZ += __shfl_xor(aZ, off); aN += __shfl_xor(aN, off);
    }

    // ---- gates on group-lead lanes (PyTorch order r,z,n); exact own-state hp
    float hv = 0.f;
    if (gl == 0) {
      float r = sigm(gaR + biR + aR + bhR);
      float z = sigm(gaZ + biZ + aZ + bhZ);
      float n = tanh_f(gaN + biN + r * (aN + bhN));
      hv = (1.f - z) * n + z * hp;
      hp = hv;
      if (t == L_SEQ - 1) hout[dom * HDIM + i4 + grp] = hv;
    }
    // collect the wave's 4 h_new values onto lane 0, publish as ONE 8B store
    float h0 = __shfl(hv, 0), h1 = __shfl(hv, 16), h2 = __shfl(hv, 32), h3 = __shfl(hv, 48);
    const unsigned tag = (unsigned)((t >> 1) & 1);
    if (lane == 0) {
      unsigned w01 = ((unsigned)f2bf(h0) | ((unsigned)f2bf(h1) << 16));
      unsigned w23 = ((unsigned)f2bf(h2) | ((unsigned)f2bf(h3) << 16));
      w01 = (w01 & ~1u) | tag;
      w23 = (w23 & ~1u) | tag;
      st8_sc1(pub + b * PUBW + dom * 512 + (i4 >> 1), w01, w23);
    }
    // no trailing barrier: Hs double-buffered; causality proof in header
  }
}

// ---------------------------------------------------------------------------
// k_head1: per output unit r of W2: hq4[r][c] = relu(Ht[c] . W2[r] + b2[r])
// Ht[0]=|hAf-hBf| Ht[1]=hAf*hBf Ht[2]=|hAb-hBb| Ht[3]=hAb*hBb
// hout layout: [dom][i], dom=(dir<<1)|sent -> hAf=+0, hBf=+H, hAb=+2H, hBb=+3H
// ---------------------------------------------------------------------------
__global__ void k_head1(const float* __restrict__ h, const float* __restrict__ W2,
                        const float* __restrict__ b2, float* __restrict__ hq4) {
  __shared__ float red[4][4];
  const int r = blockIdx.x, tid = threadIdx.x;
  const int lane = tid & 63, wid = tid >> 6;
  const float* hAf = h;
  const float* hBf = h + HDIM;
  const float* hAb = h + 2 * HDIM;
  const float* hBb = h + 3 * HDIM;
  float4 w  = *(const float4*)&W2[(size_t)r * HDIM + tid * 4];
  float4 af = *(const float4*)&hAf[tid * 4];
  float4 bf = *(const float4*)&hBf[tid * 4];
  float4 ab = *(const float4*)&hAb[tid * 4];
  float4 bb = *(const float4*)&hBb[tid * 4];
  float p0 = fabsf(af.x - bf.x) * w.x + fabsf(af.y - bf.y) * w.y +
             fabsf(af.z - bf.z) * w.z + fabsf(af.w - bf.w) * w.w;
  float p1 = (af.x * bf.x) * w.x + (af.y * bf.y) * w.y +
             (af.z * bf.z) * w.z + (af.w * bf.w) * w.w;
  float p2 = fabsf(ab.x - bb.x) * w.x + fabsf(ab.y - bb.y) * w.y +
             fabsf(ab.z - bb.z) * w.z + fabsf(ab.w - bb.w) * w.w;
  float p3 = (ab.x * bb.x) * w.x + (ab.y * bb.y) * w.y +
             (ab.z * bb.z) * w.z + (ab.w * bb.w) * w.w;
#pragma unroll
  for (int off = 32; off >= 1; off >>= 1) {
    p0 += __shfl_xor(p0, off); p1 += __shfl_xor(p1, off);
    p2 += __shfl_xor(p2, off); p3 += __shfl_xor(p3, off);
  }
  if (lane == 0) { red[wid][0] = p0; red[wid][1] = p1; red[wid][2] = p2; red[wid][3] = p3; }
  __syncthreads();
  if (tid == 0) {
    float v0 = 0, v1 = 0, v2 = 0, v3 = 0;
    for (int wv = 0; wv < 4; ++wv) { v0 += red[wv][0]; v1 += red[wv][1]; v2 += red[wv][2]; v3 += red[wv][3]; }
    float b = b2[r];
    hq4[r * 4 + 0] = fmaxf(v0 + b, 0.f);
    hq4[r * 4 + 1] = fmaxf(v1 + b, 0.f);
    hq4[r * 4 + 2] = fmaxf(v2 + b, 0.f);
    hq4[r * 4 + 3] = fmaxf(v3 + b, 0.f);
  }
}

__global__ void k_head2(const float* __restrict__ hq4, const float* __restrict__ Wl,
                        const float* __restrict__ bl, float* __restrict__ out) {
  __shared__ float red[4][4];
  const int tid = threadIdx.x, lane = tid & 63, wid = tid >> 6;
  float p0 = 0, p1 = 0, p2 = 0, p3 = 0;
  for (int r = tid; r < TDIM; r += 256) {
    p0 += hq4[r * 4 + 0]; p1 += hq4[r * 4 + 1];
    p2 += hq4[r * 4 + 2]; p3 += hq4[r * 4 + 3];
  }
#pragma unroll
  for (int off = 32; off >= 1; off >>= 1) {
    p0 += __shfl_xor(p0, off); p1 += __shfl_xor(p1, off);
    p2 += __shfl_xor(p2, off); p3 += __shfl_xor(p3, off);
  }
  if (lane == 0) { red[wid][0] = p0; red[wid][1] = p1; red[wid][2] = p2; red[wid][3] = p3; }
  __syncthreads();
  if (tid == 0) {
    float v0 = 0, v1 = 0, v2 = 0, v3 = 0;
    for (int wv = 0; wv < 4; ++wv) { v0 += red[wv][0]; v1 += red[wv][1]; v2 += red[wv][2]; v3 += red[wv][3]; }
    float logit = v0 * Wl[0] + v1 * Wl[1] + v2 * Wl[2] + v3 * Wl[3] + bl[0];
    out[0] = 1.f / (1.f + __expf(-logit));
  }
}

// ---------------------------------------------------------------------------
extern "C" void kernel_launch(void* const* d_in, const int* in_sizes, int n_in,
                              void* d_out, int out_size, void* d_ws, size_t ws_size,
                              hipStream_t stream) {
  const int*   sentA  = (const int*)d_in[0];
  const int*   sentB  = (const int*)d_in[1];
  const float* hidden = (const float*)d_in[2];
  const float* emb    = (const float*)d_in[3];
  const float* w_ih_f = (const float*)d_in[4];
  const float* w_hh_f = (const float*)d_in[5];
  const float* b_ih_f = (const float*)d_in[6];
  const float* b_hh_f = (const float*)d_in[7];
  const float* w_ih_r = (const float*)d_in[8];
  const float* w_hh_r = (const float*)d_in[9];
  const float* b_ih_r = (const float*)d_in[10];
  const float* b_hh_r = (const float*)d_in[11];
  const float* W2     = (const float*)d_in[12];
  const float* b2     = (const float*)d_in[13];
  const float* Wl     = (const float*)d_in[14];
  const float* bl     = (const float*)d_in[15];
  float* out = (float*)d_out;

  // workspace layout (16B-aligned)
  char* ws = (char*)d_ws;
  unsigned short* xbf = (unsigned short*)(ws);              // 2*4096*1024*2  = 16,777,216
  unsigned short* wbf = (unsigned short*)(ws + 16777216);   // 2*3072*1024*2  = 12,582,912
  unsigned short* gxT = (unsigned short*)(ws + 29360128);   // 4*3072*4096*2  = 100,663,296
  float*    hout = (float*)(ws + 130023424);                // 4*1024*4       = 16,384
  unsigned* pub  = (unsigned*)(ws + 130039808);             // 2*2048*4       = 16,384
  float*    hq4  = (float*)(ws + 130056192);                // 512*4*4        = 8,192

  k_init <<<dim3(16),        256, 0, stream>>>(hidden, pub);
  k_embed<<<dim3(4096, 2),   256, 0, stream>>>(sentA, sentB, emb, xbf);
  k_castw<<<dim3(3072),      256, 0, stream>>>(w_ih_f, w_ih_r, wbf);
  k_gemm <<<dim3(24, 32, 4), 256, 0, stream>>>(wbf, xbf, gxT);
  k_scan <<<dim3(128),       512, 0, stream>>>(w_hh_f, w_hh_r, b_ih_f, b_hh_f,
                                               b_ih_r, b_hh_r, hidden, gxT, hout, pub);
  k_head1<<<dim3(512),       256, 0, stream>>>(hout, W2, b2, hq4);
  k_head2<<<dim3(1),         256, 0, stream>>>(hq4, Wl, bl, out);
}